// Round 1
// baseline (363.875 us; speedup 1.0000x reference)
//
#include <hip/hip_runtime.h>

#define B_G   100
#define N_PER 1000
#define E_PER 12000
#define NTOT  (B_G * N_PER)
#define ETOT  (B_G * E_PER)
#define KSEL  800

// ---------------------------------------------------------------- deg/count
__global__ void k_deg(const int* __restrict__ ei, const float* __restrict__ ew,
                      float* __restrict__ degsum, int* __restrict__ cnt) {
    int e = blockIdx.x * blockDim.x + threadIdx.x;
    if (e >= ETOT) return;
    int col = ei[ETOT + e];
    atomicAdd(&degsum[col], ew[e]);
    atomicAdd(&cnt[col], 1);
}

// ------------------------------------------------- per-graph scan + dinv
__global__ __launch_bounds__(1024) void k_scan(const int* __restrict__ cnt,
                                               const float* __restrict__ degsum,
                                               int* __restrict__ rowptr,
                                               float* __restrict__ dinv) {
    __shared__ int s[1024];
    int b = blockIdx.x, tid = threadIdx.x;
    int gi = b * N_PER + tid;
    int v = (tid < N_PER) ? cnt[gi] : 0;
    s[tid] = v;
    __syncthreads();
    for (int off = 1; off < 1024; off <<= 1) {
        int t = (tid >= off) ? s[tid - off] : 0;
        __syncthreads();
        s[tid] += t;
        __syncthreads();
    }
    if (tid < N_PER) {
        rowptr[gi] = b * E_PER + s[tid] - v;                 // exclusive
        dinv[gi]   = 1.0f / sqrtf(degsum[gi] + 1.0f);
    }
}

// ---------------------------------------------------------------- CSR fill
__global__ void k_fill(const int* __restrict__ ei, const float* __restrict__ ew,
                       const float* __restrict__ dinv, const int* __restrict__ rowptr,
                       int* __restrict__ cnt, int2* __restrict__ csr) {
    int e = blockIdx.x * blockDim.x + threadIdx.x;
    if (e >= ETOT) return;
    int row = ei[e], col = ei[ETOT + e];
    float cf = dinv[row] * ew[e] * dinv[col];
    int old = atomicSub(&cnt[col], 1);
    int pos = rowptr[col] + old - 1;
    csr[pos] = make_int2(row, __float_as_int(cf));
}

// ------------------------------- conv1: aggregate x (3-dim), @W1, relu, x1 partials
__global__ __launch_bounds__(256) void k_conv1(
    const float* __restrict__ x, const int2* __restrict__ csr,
    const int* __restrict__ rowptr, const float* __restrict__ dinv,
    const float* __restrict__ w1, const float* __restrict__ b1,
    float* __restrict__ h1, float* __restrict__ x1sum) {
    const int CH = 16, NPC = 63;                 // 16 chunks/graph, 63 nodes/chunk
    int b = blockIdx.x / CH, chunk = blockIdx.x % CH;
    int w = threadIdx.x >> 6, lane = threadIdx.x & 63;
    float w0 = w1[lane], w1v = w1[64 + lane], w2v = w1[128 + lane], bf = b1[lane];
    int lstart = chunk * NPC;
    int lend = min(lstart + NPC, N_PER);
    float px1 = 0.f;
    for (int li = lstart + w; li < lend; li += 4) {
        int i = b * N_PER + li;
        int s = rowptr[i];
        int e = (li == N_PER - 1) ? (b + 1) * E_PER : rowptr[i + 1];
        float p0 = 0.f, p1 = 0.f, p2 = 0.f;
        for (int k = s + lane; k < e; k += 64) {      // lanes over edges
            int2 pk = csr[k];
            float cf = __int_as_float(pk.y);
            const float* xs = x + (size_t)pk.x * 3;
            p0 += cf * xs[0]; p1 += cf * xs[1]; p2 += cf * xs[2];
        }
#pragma unroll
        for (int m = 32; m; m >>= 1) {
            p0 += __shfl_xor(p0, m);
            p1 += __shfl_xor(p1, m);
            p2 += __shfl_xor(p2, m);
        }
        float di = dinv[i], di2 = di * di;
        const float* xi = x + (size_t)i * 3;
        float a0 = p0 + di2 * xi[0];
        float a1 = p1 + di2 * xi[1];
        float a2 = p2 + di2 * xi[2];
        float hf = fmaxf(a0 * w0 + a1 * w1v + a2 * w2v + bf, 0.f);
        h1[((size_t)i << 6) + lane] = hf;
        px1 += hf;
    }
    __shared__ float sm[4][64];
    sm[w][lane] = px1;
    __syncthreads();
    if (w == 0) {
        float t = sm[0][lane] + sm[1][lane] + sm[2][lane] + sm[3][lane];
        atomicAdd(&x1sum[b * 64 + lane], t);
    }
}

// ------------- conv2: aggregate h1 (64-dim), @W2 via readlane, relu, score
__global__ __launch_bounds__(256) void k_conv2(
    const float* __restrict__ h1, const int2* __restrict__ csr,
    const int* __restrict__ rowptr, const float* __restrict__ dinv,
    const float* __restrict__ w2, const float* __restrict__ b2,
    const float* __restrict__ pw,
    float* __restrict__ h2, float* __restrict__ score) {
    int w = threadIdx.x >> 6, lane = threadIdx.x & 63;
    int gw = blockIdx.x * 4 + w;
    int nw = gridDim.x * 4;
    float w2c[64];
#pragma unroll
    for (int k = 0; k < 64; k++) w2c[k] = w2[k * 64 + lane];  // W2 column in VGPRs
    float b2f = b2[lane], pwf = pw[lane];
    float pn = pwf * pwf;
#pragma unroll
    for (int m = 32; m; m >>= 1) pn += __shfl_xor(pn, m);
    float inv_norm = 1.0f / sqrtf(pn);

    for (int i = gw; i < NTOT; i += nw) {
        int bb = i / N_PER;
        int li = i - bb * N_PER;
        int s = rowptr[i];
        int e = (li == N_PER - 1) ? (bb + 1) * E_PER : rowptr[i + 1];
        float g0 = 0.f, g1 = 0.f, g2 = 0.f, g3 = 0.f;
        for (int base = s; base < e; base += 64) {
            int nb = min(64, e - base);
            int ld = min(base + lane, ETOT - 1);
            int2 pk = csr[ld];                        // lanes prefetch edge metadata
            int   srcl = pk.x;
            int   cfl  = pk.y;
            int kk = 0;
            for (; kk + 4 <= nb; kk += 4) {           // 4-way ILP on L2 gathers
                int s0 = __builtin_amdgcn_readlane(srcl, kk + 0);
                int s1 = __builtin_amdgcn_readlane(srcl, kk + 1);
                int s2 = __builtin_amdgcn_readlane(srcl, kk + 2);
                int s3 = __builtin_amdgcn_readlane(srcl, kk + 3);
                float c0 = __int_as_float(__builtin_amdgcn_readlane(cfl, kk + 0));
                float c1 = __int_as_float(__builtin_amdgcn_readlane(cfl, kk + 1));
                float c2 = __int_as_float(__builtin_amdgcn_readlane(cfl, kk + 2));
                float c3 = __int_as_float(__builtin_amdgcn_readlane(cfl, kk + 3));
                g0 += c0 * h1[((size_t)s0 << 6) + lane];
                g1 += c1 * h1[((size_t)s1 << 6) + lane];
                g2 += c2 * h1[((size_t)s2 << 6) + lane];
                g3 += c3 * h1[((size_t)s3 << 6) + lane];
            }
            for (; kk < nb; ++kk) {
                int s0 = __builtin_amdgcn_readlane(srcl, kk);
                float c0 = __int_as_float(__builtin_amdgcn_readlane(cfl, kk));
                g0 += c0 * h1[((size_t)s0 << 6) + lane];
            }
        }
        float di = dinv[i];
        float g = (g0 + g1) + (g2 + g3) + di * di * h1[((size_t)i << 6) + lane];
        float y = b2f;
#pragma unroll
        for (int k = 0; k < 64; k++) {                // g @ W2 via readlane broadcast
            float gk = __int_as_float(__builtin_amdgcn_readlane(__float_as_int(g), k));
            y += gk * w2c[k];
        }
        float hv = fmaxf(y, 0.f);
        h2[((size_t)i << 6) + lane] = hv;
        float t = hv * pwf;
#pragma unroll
        for (int m = 32; m; m >>= 1) t += __shfl_xor(t, m);
        if (lane == 0) score[i] = tanhf(t * inv_norm);
    }
}

// --------------------- topk (bitonic sort 1024) + x2 + z + MLP + sigmoid
__global__ __launch_bounds__(1024) void k_topk(
    const float* __restrict__ score, const float* __restrict__ h2,
    const float* __restrict__ x1sum,
    const float* __restrict__ l1w, const float* __restrict__ l1b,
    const float* __restrict__ l2w, const float* __restrict__ l2b,
    const float* __restrict__ l3w, const float* __restrict__ l3b,
    float* __restrict__ out) {
    __shared__ unsigned long long keys[1024];
    __shared__ float red[1024];
    __shared__ float zbuf[64], a1buf[64], a2buf[32];
    int b = blockIdx.x, tid = threadIdx.x;
    if (tid < N_PER) {
        float sc = score[b * N_PER + tid];
        unsigned bits = __float_as_uint(sc);
        unsigned u = (bits & 0x80000000u) ? ~bits : (bits | 0x80000000u);
        keys[tid] = ((unsigned long long)u << 32) | (unsigned)(1023 - tid);
    } else {
        keys[tid] = 0ull;          // below any real score
    }
    __syncthreads();
    for (int k = 2; k <= 1024; k <<= 1) {
        for (int j = k >> 1; j > 0; j >>= 1) {
            int ixj = tid ^ j;
            if (ixj > tid) {
                unsigned long long a = keys[tid], c = keys[ixj];
                bool desc = ((tid & k) == 0);
                if (desc ? (a < c) : (a > c)) { keys[tid] = c; keys[ixj] = a; }
            }
            __syncthreads();
        }
    }
    // weighted sum over top-K (order-free mean)
    int f = tid & 63, w = tid >> 6;
    float acc = 0.f;
    for (int r = w; r < KSEL; r += 16) {
        unsigned long long key = keys[r];
        int idx = 1023 - (int)(key & 0xFFFFFFFFu);
        unsigned u = (unsigned)(key >> 32);
        unsigned bits = (u & 0x80000000u) ? (u & 0x7FFFFFFFu) : ~u;
        float val = __uint_as_float(bits);
        acc += val * h2[((size_t)(b * N_PER + idx) << 6) + f];
    }
    red[tid] = acc;
    __syncthreads();
    if (tid < 64) {
        float s2 = 0.f;
        for (int ww = 0; ww < 16; ww++) s2 += red[ww * 64 + tid];
        float x2 = s2 * (1.0f / KSEL);
        zbuf[tid] = x1sum[b * 64 + tid] * (1.0f / N_PER) + x2;
    }
    __syncthreads();
    if (tid < 64) {
        float a = l1b[tid];
        for (int k = 0; k < 64; k++) a += zbuf[k] * l1w[k * 64 + tid];
        a1buf[tid] = fmaxf(a, 0.f);
    }
    __syncthreads();
    if (tid < 32) {
        float a = l2b[tid];
        for (int k = 0; k < 64; k++) a += a1buf[k] * l2w[k * 32 + tid];
        a2buf[tid] = fmaxf(a, 0.f);
    }
    __syncthreads();
    if (tid == 0) {
        float t = l3b[0];
        for (int k = 0; k < 32; k++) t += a2buf[k] * l3w[k];
        out[b] = 1.0f / (1.0f + expf(-t));
    }
}

extern "C" void kernel_launch(void* const* d_in, const int* in_sizes, int n_in,
                              void* d_out, int out_size, void* d_ws, size_t ws_size,
                              hipStream_t stream) {
    const float* x   = (const float*)d_in[0];
    const int*   ei  = (const int*)d_in[1];
    const float* ew  = (const float*)d_in[2];
    const float* c1w = (const float*)d_in[4];
    const float* c1b = (const float*)d_in[5];
    const float* c2w = (const float*)d_in[6];
    const float* c2b = (const float*)d_in[7];
    const float* pw  = (const float*)d_in[8];
    const float* l1w = (const float*)d_in[9];
    const float* l1b = (const float*)d_in[10];
    const float* l2w = (const float*)d_in[11];
    const float* l2b = (const float*)d_in[12];
    const float* l3w = (const float*)d_in[13];
    const float* l3b = (const float*)d_in[14];
    float* out = (float*)d_out;

    char* ws = (char*)d_ws;
    size_t o = 0;
    auto alloc = [&](size_t bytes) { size_t cur = o; o += (bytes + 511) & ~(size_t)511; return cur; };
    float* degsum = (float*)(ws + alloc((size_t)NTOT * 4));
    int*   cnt    = (int*)  (ws + alloc((size_t)NTOT * 4));
    float* x1sum  = (float*)(ws + alloc((size_t)B_G * 64 * 4));
    size_t zero_bytes = o;                      // degsum+cnt+x1sum must start at 0
    float* dinv   = (float*)(ws + alloc((size_t)NTOT * 4));
    int*   rowptr = (int*)  (ws + alloc((size_t)NTOT * 4));
    int2*  csr    = (int2*) (ws + alloc((size_t)ETOT * 8));
    float* h1     = (float*)(ws + alloc((size_t)NTOT * 64 * 4));
    float* h2     = (float*)(ws + alloc((size_t)NTOT * 64 * 4));
    float* score  = (float*)(ws + alloc((size_t)NTOT * 4));
    (void)ws_size; (void)in_sizes; (void)n_in; (void)out_size;

    hipMemsetAsync(d_ws, 0, zero_bytes, stream);

    int eb = (ETOT + 255) / 256;
    k_deg  <<<eb, 256, 0, stream>>>(ei, ew, degsum, cnt);
    k_scan <<<B_G, 1024, 0, stream>>>(cnt, degsum, rowptr, dinv);
    k_fill <<<eb, 256, 0, stream>>>(ei, ew, dinv, rowptr, cnt, csr);
    k_conv1<<<B_G * 16, 256, 0, stream>>>(x, csr, rowptr, dinv, c1w, c1b, h1, x1sum);
    k_conv2<<<2048, 256, 0, stream>>>(h1, csr, rowptr, dinv, c2w, c2b, pw, h2, score);
    k_topk <<<B_G, 1024, 0, stream>>>(score, h2, x1sum, l1w, l1b, l2w, l2b, l3w, l3b, out);
}

// Round 2
// 290.912 us; speedup vs baseline: 1.2508x; 1.2508x over previous
//
#include <hip/hip_runtime.h>

#define B_G   100
#define N_PER 1000
#define E_PER 12000
#define NTOT  (B_G * N_PER)
#define ETOT  (B_G * E_PER)
#define KSEL  800

typedef __attribute__((ext_vector_type(8))) short short8;
typedef __attribute__((ext_vector_type(4))) float float4_;

__device__ __forceinline__ unsigned short f2bf(float f) {
    unsigned u = __float_as_uint(f);
    u += 0x7fffu + ((u >> 16) & 1u);          // RNE
    return (unsigned short)(u >> 16);
}
__device__ __forceinline__ float bf2f(unsigned short h) {
    return __uint_as_float(((unsigned)h) << 16);
}

// ---------------- fused deg + scan + CSR fill, one block per graph ----------
__global__ __launch_bounds__(1024) void k_build(
    const int* __restrict__ ei, const float* __restrict__ ew,
    float* __restrict__ dinv_g, int* __restrict__ rowp_g, int2* __restrict__ csr) {
    __shared__ int   s[1024];       // edge counts -> inclusive scan
    __shared__ float cntf[N_PER];   // sum of edge weights per dst
    __shared__ int   posc[N_PER];   // fill cursor (starts at exclusive scan)
    __shared__ float dl[N_PER];
    int b = blockIdx.x, tid = threadIdx.x;
    int gbase = b * N_PER, ebase = b * E_PER;
    s[tid] = 0;
    if (tid < N_PER) cntf[tid] = 0.f;
    __syncthreads();
    for (int e0 = tid; e0 < E_PER; e0 += 1024) {
        int dst = ei[ETOT + ebase + e0] - gbase;
        atomicAdd(&s[dst], 1);
        atomicAdd(&cntf[dst], ew[ebase + e0]);
    }
    __syncthreads();
    int v = s[tid];
    for (int off = 1; off < 1024; off <<= 1) {   // inclusive scan ladder
        int t = (tid >= off) ? s[tid - off] : 0;
        __syncthreads();
        s[tid] += t;
        __syncthreads();
    }
    if (tid < N_PER) {
        int excl = s[tid] - v;
        posc[tid] = excl;
        rowp_g[gbase + tid] = excl;              // LOCAL exclusive offset
        float di = rsqrtf(cntf[tid] + 1.0f);
        dl[tid] = di;
        dinv_g[gbase + tid] = di;
    }
    __syncthreads();
    for (int e0 = tid; e0 < E_PER; e0 += 1024) {
        int src = ei[ebase + e0] - gbase;
        int dst = ei[ETOT + ebase + e0] - gbase;
        float cf = dl[src] * ew[ebase + e0] * dl[dst];
        int p = atomicAdd(&posc[dst], 1);
        csr[ebase + p] = make_int2(src, __float_as_int(cf));  // src LOCAL
    }
}

// ---------------- conv1: per-graph block, LDS scatter in 3-dim space --------
__global__ __launch_bounds__(1024) void k_conv1(
    const int* __restrict__ ei, const float* __restrict__ ew,
    const float* __restrict__ x, const float* __restrict__ dinv_g,
    const float* __restrict__ w1, const float* __restrict__ b1,
    unsigned short* __restrict__ h1b, float* __restrict__ x1sum) {
    __shared__ float xl[N_PER * 3];
    __shared__ float agg[N_PER * 3];
    __shared__ float dl[N_PER];
    __shared__ float sred[16][64];
    int b = blockIdx.x, tid = threadIdx.x;
    int gbase = b * N_PER, ebase = b * E_PER;
    for (int i = tid; i < N_PER * 3; i += 1024) {
        xl[i]  = x[(size_t)gbase * 3 + i];
        agg[i] = 0.f;
    }
    if (tid < N_PER) dl[tid] = dinv_g[gbase + tid];
    __syncthreads();
    for (int e0 = tid; e0 < E_PER; e0 += 1024) {
        int src = ei[ebase + e0] - gbase;
        int dst = ei[ETOT + ebase + e0] - gbase;
        float cf = dl[src] * ew[ebase + e0] * dl[dst];
        atomicAdd(&agg[dst * 3 + 0], cf * xl[src * 3 + 0]);
        atomicAdd(&agg[dst * 3 + 1], cf * xl[src * 3 + 1]);
        atomicAdd(&agg[dst * 3 + 2], cf * xl[src * 3 + 2]);
    }
    __syncthreads();
    int f = tid & 63, wr = tid >> 6;
    float w0 = w1[f], w1v = w1[64 + f], w2v = w1[128 + f], bf = b1[f];
    float px = 0.f;
    for (int node = wr; node < N_PER; node += 16) {
        float di = dl[node], di2 = di * di;
        float a0 = agg[node * 3 + 0] + di2 * xl[node * 3 + 0];
        float a1 = agg[node * 3 + 1] + di2 * xl[node * 3 + 1];
        float a2 = agg[node * 3 + 2] + di2 * xl[node * 3 + 2];
        float h = fmaxf(a0 * w0 + a1 * w1v + a2 * w2v + bf, 0.f);
        h1b[(size_t)(gbase + node) * 64 + f] = f2bf(h);
        px += h;
    }
    sred[wr][f] = px;
    __syncthreads();
    if (tid < 64) {
        float t = 0.f;
        for (int r = 0; r < 16; r++) t += sred[r][tid];
        x1sum[b * 64 + tid] = t;                 // no atomics, no memset needed
    }
}

// -------- conv2: gather-aggregate (bf16) + W2 via MFMA, per-graph blocks ----
__global__ __launch_bounds__(256) void k_conv2(
    const unsigned short* __restrict__ h1b, const int2* __restrict__ csr,
    const int* __restrict__ rowp_g, const float* __restrict__ dinv_g,
    const float* __restrict__ w2, const float* __restrict__ b2,
    const float* __restrict__ pw,
    unsigned short* __restrict__ h2b, float* __restrict__ score) {
    // swizzle: all 16 chunks of graph g land on XCD g%8 (blockIdx%8 heuristic)
    int bid = blockIdx.x;
    int xcd = bid & 7, q = bid >> 3;
    int chunk = q / 13, gdiv = q % 13;
    int g = gdiv * 8 + xcd;
    if (g >= B_G) return;
    int w = threadIdx.x >> 6, lane = threadIdx.x & 63;
    int kgrp = lane >> 4, nloc = lane & 15;
    int gbase = g * N_PER, ebase = g * E_PER;
    int nbase = (chunk * 4 + w) * 16;            // 16-node tile per wave

    // B fragments: W2[k][n], k-slice (kgrp*8+j), n = c*16+nloc  (32 VGPRs)
    short8 Bf[2][4];
#pragma unroll
    for (int kh = 0; kh < 2; ++kh)
#pragma unroll
        for (int c = 0; c < 4; ++c) {
            short8 t;
#pragma unroll
            for (int j = 0; j < 8; ++j)
                t[j] = (short)f2bf(w2[(kh * 32 + kgrp * 8 + j) * 64 + c * 16 + nloc]);
            Bf[kh][c] = t;
        }
    float b2c[4], pwc[4];
#pragma unroll
    for (int c = 0; c < 4; ++c) {
        b2c[c] = b2[c * 16 + nloc];
        pwc[c] = pw[c * 16 + nloc];
    }
    float invn;
    {
        float p = pw[lane], pn = p * p;
#pragma unroll
        for (int m = 32; m; m >>= 1) pn += __shfl_xor(pn, m);
        invn = rsqrtf(pn);
    }

    __shared__ float gld[4][16][68];             // +4 pad: b128 reads 2-way only
    // --- aggregation: wave-per-node, lane = feature ---
    for (int r = 0; r < 16; ++r) {
        int li = nbase + r;
        float acc = 0.f;
        if (li < N_PER) {
            int i = gbase + li;
            int s0 = ebase + rowp_g[i];
            int e0 = ebase + ((li == N_PER - 1) ? E_PER : rowp_g[i + 1]);
            float g0 = 0.f, g1 = 0.f, g2 = 0.f, g3 = 0.f;
            for (int base = s0; base < e0; base += 64) {
                int nb = min(64, e0 - base);
                int2 pk = csr[min(base + lane, ETOT - 1)];
                int srcl = pk.x, cfl = pk.y;
                int kk = 0;
                for (; kk + 4 <= nb; kk += 4) {
                    int a0 = __builtin_amdgcn_readlane(srcl, kk + 0);
                    int a1 = __builtin_amdgcn_readlane(srcl, kk + 1);
                    int a2 = __builtin_amdgcn_readlane(srcl, kk + 2);
                    int a3 = __builtin_amdgcn_readlane(srcl, kk + 3);
                    float c0 = __int_as_float(__builtin_amdgcn_readlane(cfl, kk + 0));
                    float c1 = __int_as_float(__builtin_amdgcn_readlane(cfl, kk + 1));
                    float c2 = __int_as_float(__builtin_amdgcn_readlane(cfl, kk + 2));
                    float c3 = __int_as_float(__builtin_amdgcn_readlane(cfl, kk + 3));
                    g0 += c0 * bf2f(h1b[(size_t)(gbase + a0) * 64 + lane]);
                    g1 += c1 * bf2f(h1b[(size_t)(gbase + a1) * 64 + lane]);
                    g2 += c2 * bf2f(h1b[(size_t)(gbase + a2) * 64 + lane]);
                    g3 += c3 * bf2f(h1b[(size_t)(gbase + a3) * 64 + lane]);
                }
                for (; kk < nb; ++kk) {
                    int a0 = __builtin_amdgcn_readlane(srcl, kk);
                    float c0 = __int_as_float(__builtin_amdgcn_readlane(cfl, kk));
                    g0 += c0 * bf2f(h1b[(size_t)(gbase + a0) * 64 + lane]);
                }
            }
            float di = dinv_g[i];
            acc = (g0 + g1) + (g2 + g3) + di * di * bf2f(h1b[(size_t)i * 64 + lane]);
        }
        gld[w][r][lane] = acc;                   // wave-private slice: no barrier
    }
    // --- A fragments from LDS, then 8 MFMAs ---
    short8 Af[2];
#pragma unroll
    for (int kh = 0; kh < 2; ++kh) {
        short8 t;
#pragma unroll
        for (int j = 0; j < 8; ++j)
            t[j] = (short)f2bf(gld[w][nloc][kh * 32 + kgrp * 8 + j]);
        Af[kh] = t;
    }
    float4_ accv[4];
#pragma unroll
    for (int c = 0; c < 4; ++c) accv[c] = (float4_){0.f, 0.f, 0.f, 0.f};
#pragma unroll
    for (int kh = 0; kh < 2; ++kh)
#pragma unroll
        for (int c = 0; c < 4; ++c)
            accv[c] = __builtin_amdgcn_mfma_f32_16x16x32_bf16(Af[kh], Bf[kh][c], accv[c], 0, 0, 0);
    // --- epilogue: bias, relu, h2 store, score ---
#pragma unroll
    for (int r = 0; r < 4; ++r) {
        int li2 = nbase + kgrp * 4 + r;          // C layout: row=(lane>>4)*4+reg
        bool valid = li2 < N_PER;
        float sp = 0.f;
#pragma unroll
        for (int c = 0; c < 4; ++c) {
            float hv = fmaxf(accv[c][r] + b2c[c], 0.f);
            sp += hv * pwc[c];
            if (valid) h2b[(size_t)(gbase + li2) * 64 + c * 16 + nloc] = f2bf(hv);
        }
#pragma unroll
        for (int m = 1; m < 16; m <<= 1) sp += __shfl_xor(sp, m);
        if (valid && nloc == 0) score[gbase + li2] = tanhf(sp * invn);
    }
}

// --------------------- topk (bitonic 1024) + x2 + MLP + sigmoid -------------
__global__ __launch_bounds__(1024) void k_topk(
    const float* __restrict__ score, const unsigned short* __restrict__ h2b,
    const float* __restrict__ x1sum,
    const float* __restrict__ l1w, const float* __restrict__ l1b,
    const float* __restrict__ l2w, const float* __restrict__ l2b,
    const float* __restrict__ l3w, const float* __restrict__ l3b,
    float* __restrict__ out) {
    __shared__ unsigned long long keys[1024];
    __shared__ float red[1024];
    __shared__ float zbuf[64], a1buf[64], a2buf[32];
    int b = blockIdx.x, tid = threadIdx.x;
    if (tid < N_PER) {
        float sc = score[b * N_PER + tid];
        unsigned bits = __float_as_uint(sc);
        unsigned u = (bits & 0x80000000u) ? ~bits : (bits | 0x80000000u);
        keys[tid] = ((unsigned long long)u << 32) | (unsigned)(1023 - tid);
    } else {
        keys[tid] = 0ull;
    }
    __syncthreads();
    for (int k = 2; k <= 1024; k <<= 1) {
        for (int j = k >> 1; j > 0; j >>= 1) {
            int ixj = tid ^ j;
            if (ixj > tid) {
                unsigned long long a = keys[tid], c = keys[ixj];
                bool desc = ((tid & k) == 0);
                if (desc ? (a < c) : (a > c)) { keys[tid] = c; keys[ixj] = a; }
            }
            __syncthreads();
        }
    }
    int f = tid & 63, w = tid >> 6;
    float acc = 0.f;
    for (int r = w; r < KSEL; r += 16) {
        unsigned long long key = keys[r];
        int idx = 1023 - (int)(key & 0xFFFFFFFFu);
        unsigned u = (unsigned)(key >> 32);
        unsigned bits = (u & 0x80000000u) ? (u & 0x7FFFFFFFu) : ~u;
        float val = __uint_as_float(bits);
        acc += val * bf2f(h2b[(size_t)(b * N_PER + idx) * 64 + f]);
    }
    red[tid] = acc;
    __syncthreads();
    if (tid < 64) {
        float s2 = 0.f;
        for (int ww = 0; ww < 16; ww++) s2 += red[ww * 64 + tid];
        float x2 = s2 * (1.0f / KSEL);
        zbuf[tid] = x1sum[b * 64 + tid] * (1.0f / N_PER) + x2;
    }
    __syncthreads();
    if (tid < 64) {
        float a = l1b[tid];
        for (int k = 0; k < 64; k++) a += zbuf[k] * l1w[k * 64 + tid];
        a1buf[tid] = fmaxf(a, 0.f);
    }
    __syncthreads();
    if (tid < 32) {
        float a = l2b[tid];
        for (int k = 0; k < 64; k++) a += a1buf[k] * l2w[k * 32 + tid];
        a2buf[tid] = fmaxf(a, 0.f);
    }
    __syncthreads();
    if (tid == 0) {
        float t = l3b[0];
        for (int k = 0; k < 32; k++) t += a2buf[k] * l3w[k];
        out[b] = 1.0f / (1.0f + expf(-t));
    }
}

extern "C" void kernel_launch(void* const* d_in, const int* in_sizes, int n_in,
                              void* d_out, int out_size, void* d_ws, size_t ws_size,
                              hipStream_t stream) {
    const float* x   = (const float*)d_in[0];
    const int*   ei  = (const int*)d_in[1];
    const float* ew  = (const float*)d_in[2];
    const float* c1w = (const float*)d_in[4];
    const float* c1b = (const float*)d_in[5];
    const float* c2w = (const float*)d_in[6];
    const float* c2b = (const float*)d_in[7];
    const float* pw  = (const float*)d_in[8];
    const float* l1w = (const float*)d_in[9];
    const float* l1b = (const float*)d_in[10];
    const float* l2w = (const float*)d_in[11];
    const float* l2b = (const float*)d_in[12];
    const float* l3w = (const float*)d_in[13];
    const float* l3b = (const float*)d_in[14];
    float* out = (float*)d_out;

    char* ws = (char*)d_ws;
    size_t o = 0;
    auto alloc = [&](size_t bytes) { size_t cur = o; o += (bytes + 511) & ~(size_t)511; return cur; };
    float*          dinv  = (float*)(ws + alloc((size_t)NTOT * 4));
    int*            rowp  = (int*)  (ws + alloc((size_t)NTOT * 4));
    int2*           csr   = (int2*) (ws + alloc((size_t)ETOT * 8));
    unsigned short* h1b   = (unsigned short*)(ws + alloc((size_t)NTOT * 64 * 2));
    unsigned short* h2b   = (unsigned short*)(ws + alloc((size_t)NTOT * 64 * 2));
    float*          score = (float*)(ws + alloc((size_t)NTOT * 4));
    float*          x1sum = (float*)(ws + alloc((size_t)B_G * 64 * 4));
    (void)ws_size; (void)in_sizes; (void)n_in; (void)out_size;

    k_build<<<B_G, 1024, 0, stream>>>(ei, ew, dinv, rowp, csr);
    k_conv1<<<B_G, 1024, 0, stream>>>(ei, ew, x, dinv, c1w, c1b, h1b, x1sum);
    k_conv2<<<1664, 256, 0, stream>>>(h1b, csr, rowp, dinv, c2w, c2b, pw, h2b, score);
    k_topk <<<B_G, 1024, 0, stream>>>(score, h2b, x1sum, l1w, l1b, l2w, l2b, l3w, l3b, out);
}

// Round 3
// 259.601 us; speedup vs baseline: 1.4017x; 1.1206x over previous
//
#include <hip/hip_runtime.h>

#define B_G   100
#define N_PER 1000
#define E_PER 12000
#define NTOT  (B_G * N_PER)
#define ETOT  (B_G * E_PER)
#define KSEL  800

typedef __attribute__((ext_vector_type(8))) short short8;
typedef __attribute__((ext_vector_type(4))) short short4_;
typedef __attribute__((ext_vector_type(4))) float float4_;

__device__ __forceinline__ unsigned short f2bf(float f) {
    unsigned u = __float_as_uint(f);
    u += 0x7fffu + ((u >> 16) & 1u);          // RNE
    return (unsigned short)(u >> 16);
}
__device__ __forceinline__ float bf2f(unsigned short h) {
    return __uint_as_float(((unsigned)h) << 16);
}

// ====== fused: deg-count + scan + CSR fill + conv1 (LDS scatter) + x1sum ====
__global__ __launch_bounds__(1024) void k_pre(
    const int* __restrict__ ei, const float* __restrict__ ew,
    const float* __restrict__ x,
    const float* __restrict__ w1, const float* __restrict__ b1,
    const float* __restrict__ w2,
    float* __restrict__ dinv_g, int* __restrict__ rowp_g, int2* __restrict__ csr,
    unsigned short* __restrict__ h1b, float* __restrict__ x1sum,
    unsigned short* __restrict__ w2t) {
    __shared__ int   cnts[1024];
    __shared__ float wsum[N_PER];
    __shared__ int   posc[N_PER];
    __shared__ float dl[N_PER];
    __shared__ float xl[N_PER * 3];
    __shared__ float agg[N_PER * 3];
    __shared__ float sred[16][64];
    int b = blockIdx.x, tid = threadIdx.x;
    int gbase = b * N_PER, ebase = b * E_PER;

    if (b == 0) {  // one-time: W2 transposed to bf16, [n][k] contiguous in k
        for (int i = tid; i < 64 * 64; i += 1024) {
            int n = i >> 6, k = i & 63;
            w2t[n * 64 + k] = f2bf(w2[k * 64 + n]);
        }
    }
    cnts[tid] = 0;
    if (tid < N_PER) wsum[tid] = 0.f;
    for (int i = tid; i < N_PER * 3; i += 1024) {
        xl[i]  = x[(size_t)gbase * 3 + i];
        agg[i] = 0.f;
    }
    __syncthreads();
    for (int e = tid; e < E_PER; e += 1024) {
        int dst = ei[ETOT + ebase + e] - gbase;
        atomicAdd(&cnts[dst], 1);
        atomicAdd(&wsum[dst], ew[ebase + e]);
    }
    __syncthreads();
    int v = cnts[tid];
    for (int off = 1; off < 1024; off <<= 1) {     // inclusive scan
        int t = (tid >= off) ? cnts[tid - off] : 0;
        __syncthreads();
        cnts[tid] += t;
        __syncthreads();
    }
    if (tid < N_PER) {
        int excl = cnts[tid] - v;
        posc[tid] = excl;
        rowp_g[gbase + tid] = excl;               // LOCAL exclusive offsets
        float di = rsqrtf(wsum[tid] + 1.0f);
        dl[tid] = di;
        dinv_g[gbase + tid] = di;
    }
    __syncthreads();
    for (int e = tid; e < E_PER; e += 1024) {     // fill CSR + conv1 scatter
        int src = ei[ebase + e] - gbase;
        int dst = ei[ETOT + ebase + e] - gbase;
        float cf = dl[src] * ew[ebase + e] * dl[dst];
        int p = atomicAdd(&posc[dst], 1);
        csr[ebase + p] = make_int2(src, __float_as_int(cf));
        atomicAdd(&agg[dst * 3 + 0], cf * xl[src * 3 + 0]);
        atomicAdd(&agg[dst * 3 + 1], cf * xl[src * 3 + 1]);
        atomicAdd(&agg[dst * 3 + 2], cf * xl[src * 3 + 2]);
    }
    __syncthreads();
    int f = tid & 63, wr = tid >> 6;
    float w0 = w1[f], w1v = w1[64 + f], w2v = w1[128 + f], bf = b1[f];
    float px = 0.f;
    for (int node = wr; node < N_PER; node += 16) {
        float di = dl[node], di2 = di * di;
        float a0 = agg[node * 3 + 0] + di2 * xl[node * 3 + 0];
        float a1 = agg[node * 3 + 1] + di2 * xl[node * 3 + 1];
        float a2 = agg[node * 3 + 2] + di2 * xl[node * 3 + 2];
        float h = fmaxf(a0 * w0 + a1 * w1v + a2 * w2v + bf, 0.f);
        h1b[(size_t)(gbase + node) * 64 + f] = f2bf(h);
        px += h;
    }
    sred[wr][f] = px;
    __syncthreads();
    if (tid < 64) {
        float t = 0.f;
        for (int r = 0; r < 16; r++) t += sred[r][tid];
        x1sum[b * 64 + tid] = t;
    }
}

// ====== conv2: h1 slice LDS-resident, scalar edge loads, W2 via MFMA ========
__global__ __launch_bounds__(1024) void k_conv2(
    const unsigned short* __restrict__ h1b, const int2* __restrict__ csr,
    const int* __restrict__ rowp_g, const float* __restrict__ dinv_g,
    const unsigned short* __restrict__ w2t, const float* __restrict__ b2,
    const float* __restrict__ pw,
    unsigned short* __restrict__ h2b, float* __restrict__ score) {
    __shared__ unsigned short h1s[N_PER * 64];      // 128000 B
    __shared__ unsigned short stg[16][16 * 68];     // 34816 B, row stride 68
    int g = blockIdx.x >> 1, half = blockIdx.x & 1;
    int tid = threadIdx.x, w = tid >> 6, lane = tid & 63;
    int kgrp = lane >> 4, nloc = lane & 15;
    int gbase = g * N_PER, ebase = g * E_PER;

    // stage h1 slice -> LDS (coalesced 16B loads)
    {
        const int4* s4 = (const int4*)(h1b + (size_t)gbase * 64);
        int4* d4 = (int4*)h1s;
        for (int i = tid; i < N_PER * 64 / 8; i += 1024) d4[i] = s4[i];
    }
    // B fragments: W2t[n][k], 16B direct loads (values bf16 already)
    short8 Bf[2][4];
    const short8* w2t8 = (const short8*)w2t;
#pragma unroll
    for (int kh = 0; kh < 2; ++kh)
#pragma unroll
        for (int c = 0; c < 4; ++c)
            Bf[kh][c] = w2t8[((c * 16 + nloc) * 64 + kh * 32 + kgrp * 8) >> 3];
    float b2c[4], pwc[4];
#pragma unroll
    for (int c = 0; c < 4; ++c) {
        b2c[c] = b2[c * 16 + nloc];
        pwc[c] = pw[c * 16 + nloc];
    }
    float invn;
    {
        float p = pw[lane], pn = p * p;
#pragma unroll
        for (int m = 32; m; m >>= 1) pn += __shfl_xor(pn, m);
        invn = rsqrtf(pn);
    }
    __syncthreads();

    unsigned short* stw = &stg[w][0];
    int tlo = half * 32, thi = min(63, tlo + 32);
    for (int t = tlo + w; t < thi; t += 16) {
        // ---- aggregate 16 nodes (lane = feature), write bf16 rows to stage
        for (int r = 0; r < 16; ++r) {
            int li = t * 16 + r;
            float a0 = 0.f, a1 = 0.f, a2 = 0.f, a3 = 0.f;
            if (li < N_PER) {
                int i = gbase + li;
                int s0 = __builtin_amdgcn_readfirstlane(rowp_g[i]);
                int e0 = (li == N_PER - 1) ? E_PER
                                           : __builtin_amdgcn_readfirstlane(rowp_g[i + 1]);
                float dv = dinv_g[i];
                a0 = dv * dv * bf2f(h1s[li * 64 + lane]);   // self-loop
                int k = s0;
                for (; k + 4 <= e0; k += 4) {               // uniform -> s_load
                    int2 q0 = csr[ebase + k + 0];
                    int2 q1 = csr[ebase + k + 1];
                    int2 q2 = csr[ebase + k + 2];
                    int2 q3 = csr[ebase + k + 3];
                    a0 += __int_as_float(q0.y) * bf2f(h1s[q0.x * 64 + lane]);
                    a1 += __int_as_float(q1.y) * bf2f(h1s[q1.x * 64 + lane]);
                    a2 += __int_as_float(q2.y) * bf2f(h1s[q2.x * 64 + lane]);
                    a3 += __int_as_float(q3.y) * bf2f(h1s[q3.x * 64 + lane]);
                }
                for (; k < e0; ++k) {
                    int2 q0 = csr[ebase + k];
                    a0 += __int_as_float(q0.y) * bf2f(h1s[q0.x * 64 + lane]);
                }
            }
            stw[r * 68 + lane] = f2bf((a0 + a1) + (a2 + a3));
        }
        // ---- A fragments from stage (8B-aligned pair loads), 8 MFMAs
        float4_ accv[4];
#pragma unroll
        for (int c = 0; c < 4; ++c) accv[c] = (float4_){0.f, 0.f, 0.f, 0.f};
#pragma unroll
        for (int kh = 0; kh < 2; ++kh) {
            const unsigned short* ap = stw + nloc * 68 + kh * 32 + kgrp * 8;
            short4_ lo = *(const short4_*)(ap);
            short4_ hi = *(const short4_*)(ap + 4);
            short8 Af = __builtin_shufflevector(lo, hi, 0, 1, 2, 3, 4, 5, 6, 7);
#pragma unroll
            for (int c = 0; c < 4; ++c)
                accv[c] = __builtin_amdgcn_mfma_f32_16x16x32_bf16(Af, Bf[kh][c], accv[c], 0, 0, 0);
        }
        // ---- epilogue: bias+relu, h2 store, score
#pragma unroll
        for (int r2 = 0; r2 < 4; ++r2) {
            int li2 = t * 16 + kgrp * 4 + r2;      // C: row=(lane>>4)*4+reg
            bool valid = li2 < N_PER;
            float sp = 0.f;
#pragma unroll
            for (int c = 0; c < 4; ++c) {
                float hv = fmaxf(accv[c][r2] + b2c[c], 0.f);
                sp += hv * pwc[c];
                if (valid) h2b[(size_t)(gbase + li2) * 64 + c * 16 + nloc] = f2bf(hv);
            }
#pragma unroll
            for (int m = 1; m < 16; m <<= 1) sp += __shfl_xor(sp, m);
            if (valid && nloc == 0) score[gbase + li2] = tanhf(sp * invn);
        }
    }
}

// ====== topk (bitonic 1024) + x2 + MLP + sigmoid ============================
__global__ __launch_bounds__(1024) void k_topk(
    const float* __restrict__ score, const unsigned short* __restrict__ h2b,
    const float* __restrict__ x1sum,
    const float* __restrict__ l1w, const float* __restrict__ l1b,
    const float* __restrict__ l2w, const float* __restrict__ l2b,
    const float* __restrict__ l3w, const float* __restrict__ l3b,
    float* __restrict__ out) {
    __shared__ unsigned long long keys[1024];
    __shared__ float red[1024];
    __shared__ float zbuf[64], a1buf[64], a2buf[32];
    int b = blockIdx.x, tid = threadIdx.x;
    if (tid < N_PER) {
        float sc = score[b * N_PER + tid];
        unsigned bits = __float_as_uint(sc);
        unsigned u = (bits & 0x80000000u) ? ~bits : (bits | 0x80000000u);
        keys[tid] = ((unsigned long long)u << 32) | (unsigned)(1023 - tid);
    } else {
        keys[tid] = 0ull;
    }
    __syncthreads();
    for (int k = 2; k <= 1024; k <<= 1) {
        for (int j = k >> 1; j > 0; j >>= 1) {
            int ixj = tid ^ j;
            if (ixj > tid) {
                unsigned long long a = keys[tid], c = keys[ixj];
                bool desc = ((tid & k) == 0);
                if (desc ? (a < c) : (a > c)) { keys[tid] = c; keys[ixj] = a; }
            }
            __syncthreads();
        }
    }
    int f = tid & 63, w = tid >> 6;
    float acc = 0.f;
    for (int r = w; r < KSEL; r += 16) {
        unsigned long long key = keys[r];
        int idx = 1023 - (int)(key & 0xFFFFFFFFu);
        unsigned u = (unsigned)(key >> 32);
        unsigned bits = (u & 0x80000000u) ? (u & 0x7FFFFFFFu) : ~u;
        float val = __uint_as_float(bits);
        acc += val * bf2f(h2b[(size_t)(b * N_PER + idx) * 64 + f]);
    }
    red[tid] = acc;
    __syncthreads();
    if (tid < 64) {
        float s2 = 0.f;
        for (int ww = 0; ww < 16; ww++) s2 += red[ww * 64 + tid];
        float x2 = s2 * (1.0f / KSEL);
        zbuf[tid] = x1sum[b * 64 + tid] * (1.0f / N_PER) + x2;
    }
    __syncthreads();
    if (tid < 64) {
        float a = l1b[tid];
        for (int k = 0; k < 64; k++) a += zbuf[k] * l1w[k * 64 + tid];
        a1buf[tid] = fmaxf(a, 0.f);
    }
    __syncthreads();
    if (tid < 32) {
        float a = l2b[tid];
        for (int k = 0; k < 64; k++) a += a1buf[k] * l2w[k * 32 + tid];
        a2buf[tid] = fmaxf(a, 0.f);
    }
    __syncthreads();
    if (tid == 0) {
        float t = l3b[0];
        for (int k = 0; k < 32; k++) t += a2buf[k] * l3w[k];
        out[b] = 1.0f / (1.0f + expf(-t));
    }
}

extern "C" void kernel_launch(void* const* d_in, const int* in_sizes, int n_in,
                              void* d_out, int out_size, void* d_ws, size_t ws_size,
                              hipStream_t stream) {
    const float* x   = (const float*)d_in[0];
    const int*   ei  = (const int*)d_in[1];
    const float* ew  = (const float*)d_in[2];
    const float* c1w = (const float*)d_in[4];
    const float* c1b = (const float*)d_in[5];
    const float* c2w = (const float*)d_in[6];
    const float* c2b = (const float*)d_in[7];
    const float* pw  = (const float*)d_in[8];
    const float* l1w = (const float*)d_in[9];
    const float* l1b = (const float*)d_in[10];
    const float* l2w = (const float*)d_in[11];
    const float* l2b = (const float*)d_in[12];
    const float* l3w = (const float*)d_in[13];
    const float* l3b = (const float*)d_in[14];
    float* out = (float*)d_out;

    char* ws = (char*)d_ws;
    size_t o = 0;
    auto alloc = [&](size_t bytes) { size_t cur = o; o += (bytes + 511) & ~(size_t)511; return cur; };
    float*          dinv  = (float*)(ws + alloc((size_t)NTOT * 4));
    int*            rowp  = (int*)  (ws + alloc((size_t)NTOT * 4));
    int2*           csr   = (int2*) (ws + alloc((size_t)ETOT * 8));
    unsigned short* h1b   = (unsigned short*)(ws + alloc((size_t)NTOT * 64 * 2));
    unsigned short* h2b   = (unsigned short*)(ws + alloc((size_t)NTOT * 64 * 2));
    float*          score = (float*)(ws + alloc((size_t)NTOT * 4));
    float*          x1sum = (float*)(ws + alloc((size_t)B_G * 64 * 4));
    unsigned short* w2t   = (unsigned short*)(ws + alloc((size_t)64 * 64 * 2));
    (void)ws_size; (void)in_sizes; (void)n_in; (void)out_size;

    k_pre  <<<B_G, 1024, 0, stream>>>(ei, ew, x, c1w, c1b, c2w,
                                      dinv, rowp, csr, h1b, x1sum, w2t);
    k_conv2<<<B_G * 2, 1024, 0, stream>>>(h1b, csr, rowp, dinv, w2t, c2b, pw, h2b, score);
    k_topk <<<B_G, 1024, 0, stream>>>(score, h2b, x1sum, l1w, l1b, l2w, l2b, l3w, l3b, out);
}

// Round 4
// 191.419 us; speedup vs baseline: 1.9009x; 1.3562x over previous
//
#include <hip/hip_runtime.h>

#define B_G   100
#define N_PER 1000
#define E_PER 12000
#define NTOT  (B_G * N_PER)
#define ETOT  (B_G * E_PER)
#define KSEL  800
#define EPT   12            // ceil(E_PER/1024)

typedef __attribute__((ext_vector_type(8))) short short8;
typedef __attribute__((ext_vector_type(4))) float float4_;

__device__ __forceinline__ unsigned short f2bf(float f) {
    unsigned u = __float_as_uint(f);
    u += 0x7fffu + ((u >> 16) & 1u);          // RNE
    return (unsigned short)(u >> 16);
}
__device__ __forceinline__ float bf2f(unsigned short h) {
    return __uint_as_float(((unsigned)h) << 16);
}

// ===== whole network, one block per graph, everything LDS-resident ==========
// LDS map (152832 B):
//   [0,128000)        h1s   : u16[1000*64]   h1 bf16; overwritten by h2 later
//   [128000,132096)   ends  : int[1024]      inclusive rowptr (counts scanned)
//   [132096,136192)   dl    : float[1024]    dinv
//   [136192,136448)   x1b   : float[64]      x1 mean (int16 scan temps early)
//   [136448,152832)   uA    : 16384 B union:
//       build: wsum f[1024] | posc i[1024]
//       conv1: aggv f[3000] + sred f[16*64]
//       topk : keys u64[1024] + red f[1024] + a1[64] + a2[32] + z[64]
__global__ __launch_bounds__(1024) void k_all(
    const int* __restrict__ ei, const float* __restrict__ ew,
    const float* __restrict__ x,
    const float* __restrict__ w1, const float* __restrict__ b1,
    const float* __restrict__ w2, const float* __restrict__ b2,
    const float* __restrict__ pw,
    const float* __restrict__ l1w, const float* __restrict__ l1b,
    const float* __restrict__ l2w, const float* __restrict__ l2b,
    const float* __restrict__ l3w, const float* __restrict__ l3b,
    int2* __restrict__ csr, float* __restrict__ out) {
    __shared__ __align__(16) unsigned char smem[152832];
    unsigned short* h1s = (unsigned short*)smem;
    int*   ends = (int*)(smem + 128000);
    float* dl   = (float*)(smem + 132096);
    float* x1b  = (float*)(smem + 136192);
    unsigned char* uA = smem + 136448;

    int b = blockIdx.x, tid = threadIdx.x;
    int wid = tid >> 6, lane = tid & 63;
    int gbase = b * N_PER, ebase = b * E_PER;

    // ---- load this thread's edges once into registers (coalesced) ----
    int esrc[EPT], edst[EPT]; float eww[EPT];
    int ne = (tid < (E_PER - (EPT - 1) * 1024)) ? EPT : EPT - 1;
#pragma unroll
    for (int i = 0; i < EPT; i++) {
        if (i < ne) {
            int e = tid + i * 1024;
            esrc[i] = ei[ebase + e] - gbase;
            edst[i] = ei[ETOT + ebase + e] - gbase;
            eww[i]  = ew[ebase + e];
        }
    }
    float* wsum = (float*)uA;
    int*   posc = (int*)(uA + 4096);
    ends[tid] = 0;
    wsum[tid] = 0.f;
    __syncthreads();
    // ---- count pass ----
#pragma unroll
    for (int i = 0; i < EPT; i++)
        if (i < ne) {
            atomicAdd(&ends[edst[i]], 1);
            atomicAdd(&wsum[edst[i]], eww[i]);
        }
    __syncthreads();
    // ---- shuffle-based inclusive scan of counts ----
    int v = ends[tid];
    int sc = v;
#pragma unroll
    for (int m = 1; m < 64; m <<= 1) {
        int t = __shfl_up(sc, m);
        if (lane >= m) sc += t;
    }
    int* wpart = (int*)x1b;                 // temp use
    if (lane == 63) wpart[wid] = sc;
    __syncthreads();
    if (tid < 16) {
        int s2 = wpart[tid];
#pragma unroll
        for (int m = 1; m < 16; m <<= 1) {
            int t = __shfl_up(s2, m);
            if (tid >= m) s2 += t;
        }
        wpart[tid] = s2;
    }
    __syncthreads();
    int incl = sc + (wid > 0 ? wpart[wid - 1] : 0);
    ends[tid] = incl;
    posc[tid] = incl - v;
    dl[tid] = rsqrtf(wsum[tid] + 1.0f);
    __syncthreads();
    // ---- CSR fill (global csr; L2-hot for this CU's later reads) ----
#pragma unroll
    for (int i = 0; i < EPT; i++)
        if (i < ne) {
            float cf = dl[esrc[i]] * eww[i] * dl[edst[i]];
            int p = atomicAdd(&posc[edst[i]], 1);
            csr[ebase + p] = make_int2(esrc[i], __float_as_int(cf));
        }
    __syncthreads();
    // ---- conv1: gather in 3-dim input space, thread per node ----
    float* aggv = (float*)uA;
    if (tid < N_PER) {
        int s = (tid > 0) ? ends[tid - 1] : 0;
        int e = ends[tid];
        float a0 = 0.f, a1 = 0.f, a2 = 0.f;
        for (int k = s; k < e; k++) {
            int2 q = csr[ebase + k];
            float cf = __int_as_float(q.y);
            const float* xs = x + (size_t)(gbase + q.x) * 3;
            a0 += cf * xs[0]; a1 += cf * xs[1]; a2 += cf * xs[2];
        }
        float d2 = dl[tid] * dl[tid];
        const float* xn = x + (size_t)(gbase + tid) * 3;
        aggv[tid * 3 + 0] = a0 + d2 * xn[0];
        aggv[tid * 3 + 1] = a1 + d2 * xn[1];
        aggv[tid * 3 + 2] = a2 + d2 * xn[2];
    }
    __syncthreads();
    // ---- h1 = relu(agg @ W1 + b1), bf16 into LDS; x1 partials ----
    {
        float w0 = w1[lane], w1v = w1[64 + lane], w2v = w1[128 + lane], bf = b1[lane];
        float* sred = (float*)(uA + 12288);
        float px = 0.f;
        for (int node = wid; node < N_PER; node += 16) {
            float a0 = aggv[node * 3], a1 = aggv[node * 3 + 1], a2 = aggv[node * 3 + 2];
            float h = fmaxf(a0 * w0 + a1 * w1v + a2 * w2v + bf, 0.f);
            h1s[node * 64 + lane] = f2bf(h);
            px += h;
        }
        sred[wid * 64 + lane] = px;
        __syncthreads();
        if (tid < 64) {
            float t = 0.f;
            for (int r = 0; r < 16; r++) t += sred[r * 64 + tid];
            x1b[tid] = t * (1.0f / N_PER);
        }
    }
    __syncthreads();
    // ---- conv2 aggregation directly in MFMA A-fragment layout ----
    // lane (kgrp,nloc): node li = t*16+nloc, features kh*32+kgrp*8+[0..8)
    int kgrp = lane >> 4, nloc = lane & 15;
    short8 AfS[4][2];
#pragma unroll
    for (int ti = 0; ti < 4; ti++) {
        int t = wid + ti * 16;
        if (t >= 63) continue;
        int li = t * 16 + nloc;
        bool valid = li < N_PER;
        float acc[16];
        if (valid) {
            float d2 = dl[li] * dl[li];
            const unsigned short* row = h1s + li * 64;
            short8 r0 = *(const short8*)(row + kgrp * 8);
            short8 r1 = *(const short8*)(row + 32 + kgrp * 8);
#pragma unroll
            for (int j = 0; j < 8; j++) {
                acc[j]     = d2 * bf2f((unsigned short)r0[j]);
                acc[8 + j] = d2 * bf2f((unsigned short)r1[j]);
            }
        } else {
#pragma unroll
            for (int j = 0; j < 16; j++) acc[j] = 0.f;
        }
        int s = 0, cnt = 0;
        if (valid) {
            s = (li > 0) ? ends[li - 1] : 0;
            cnt = ends[li] - s;
        }
        int mx = cnt;
#pragma unroll
        for (int m = 1; m < 16; m <<= 1) mx = max(mx, __shfl_xor(mx, m));
        int base = ebase + s;
        for (int k = 0; k < mx; k++) {
            if (k < cnt) {
                int2 q = csr[base + k];
                float cf = __int_as_float(q.y);
                const unsigned short* row = h1s + q.x * 64;
                short8 r0 = *(const short8*)(row + kgrp * 8);
                short8 r1 = *(const short8*)(row + 32 + kgrp * 8);
#pragma unroll
                for (int j = 0; j < 8; j++) {
                    acc[j]     += cf * bf2f((unsigned short)r0[j]);
                    acc[8 + j] += cf * bf2f((unsigned short)r1[j]);
                }
            }
        }
        short8 a0, a1;
#pragma unroll
        for (int j = 0; j < 8; j++) {
            a0[j] = (short)f2bf(acc[j]);
            a1[j] = (short)f2bf(acc[8 + j]);
        }
        AfS[ti][0] = a0;
        AfS[ti][1] = a1;
    }
    __syncthreads();   // all aggregation done; h1s may now be overwritten
    // ---- W2 via MFMA + epilogue (h2 -> h1s region, scores -> keys) ----
    unsigned long long* keys = (unsigned long long*)uA;
    {
        short8 Bf[2][4];
#pragma unroll
        for (int kh = 0; kh < 2; ++kh)
#pragma unroll
            for (int c = 0; c < 4; ++c) {
                short8 t;
#pragma unroll
                for (int j = 0; j < 8; ++j)
                    t[j] = (short)f2bf(w2[(kh * 32 + kgrp * 8 + j) * 64 + c * 16 + nloc]);
                Bf[kh][c] = t;
            }
        float b2c[4], pwc[4];
#pragma unroll
        for (int c = 0; c < 4; ++c) {
            b2c[c] = b2[c * 16 + nloc];
            pwc[c] = pw[c * 16 + nloc];
        }
        float invn;
        {
            float p = pw[lane], pn = p * p;
#pragma unroll
            for (int m = 32; m; m >>= 1) pn += __shfl_xor(pn, m);
            invn = rsqrtf(pn);
        }
        if (tid >= N_PER) keys[tid] = 0ull;    // pad entries
#pragma unroll
        for (int ti = 0; ti < 4; ti++) {
            int t = wid + ti * 16;
            if (t >= 63) continue;
            float4_ accv[4];
#pragma unroll
            for (int c = 0; c < 4; ++c) accv[c] = (float4_){0.f, 0.f, 0.f, 0.f};
#pragma unroll
            for (int kh = 0; kh < 2; ++kh)
#pragma unroll
                for (int c = 0; c < 4; ++c)
                    accv[c] = __builtin_amdgcn_mfma_f32_16x16x32_bf16(AfS[ti][kh], Bf[kh][c], accv[c], 0, 0, 0);
#pragma unroll
            for (int r2 = 0; r2 < 4; ++r2) {
                int li2 = t * 16 + kgrp * 4 + r2;   // C layout: row=(lane>>4)*4+reg
                bool valid2 = li2 < N_PER;
                float sp = 0.f;
#pragma unroll
                for (int c = 0; c < 4; ++c) {
                    float hv = fmaxf(accv[c][r2] + b2c[c], 0.f);
                    sp += hv * pwc[c];
                    if (valid2) h1s[li2 * 64 + c * 16 + nloc] = f2bf(hv);  // h2
                }
#pragma unroll
                for (int m = 1; m < 16; m <<= 1) sp += __shfl_xor(sp, m);
                if (valid2 && nloc == 0) {
                    float scv = tanhf(sp * invn);
                    unsigned bits = __float_as_uint(scv);
                    unsigned u = (bits & 0x80000000u) ? ~bits : (bits | 0x80000000u);
                    keys[li2] = ((unsigned long long)u << 32) | (unsigned)(1023 - li2);
                }
            }
        }
    }
    __syncthreads();
    // ---- bitonic sort 1024 keys (desc score, asc index) ----
    for (int k = 2; k <= 1024; k <<= 1) {
        for (int j = k >> 1; j > 0; j >>= 1) {
            int ixj = tid ^ j;
            if (ixj > tid) {
                unsigned long long a = keys[tid], c = keys[ixj];
                bool desc = ((tid & k) == 0);
                if (desc ? (a < c) : (a > c)) { keys[tid] = c; keys[ixj] = a; }
            }
            __syncthreads();
        }
    }
    // ---- weighted mean over top-K (h2 from LDS) + MLP ----
    float* red   = (float*)(uA + 8192);
    float* a1buf = (float*)(uA + 12288);
    float* a2buf = (float*)(uA + 12544);
    float* zbuf  = (float*)(uA + 12672);
    {
        int f = tid & 63, w16 = tid >> 6;
        float acc = 0.f;
        for (int r = w16; r < KSEL; r += 16) {
            unsigned long long key = keys[r];
            int idx = 1023 - (int)(key & 0xFFFFFFFFu);
            unsigned u = (unsigned)(key >> 32);
            unsigned bits = (u & 0x80000000u) ? (u & 0x7FFFFFFFu) : ~u;
            float val = __uint_as_float(bits);
            acc += val * bf2f(h1s[idx * 64 + f]);
        }
        red[tid] = acc;
    }
    __syncthreads();
    if (tid < 64) {
        float s2 = 0.f;
        for (int ww = 0; ww < 16; ww++) s2 += red[ww * 64 + tid];
        zbuf[tid] = x1b[tid] + s2 * (1.0f / KSEL);
    }
    __syncthreads();
    if (tid < 64) {
        float a = l1b[tid];
        for (int k = 0; k < 64; k++) a += zbuf[k] * l1w[k * 64 + tid];
        a1buf[tid] = fmaxf(a, 0.f);
    }
    __syncthreads();
    if (tid < 32) {
        float a = l2b[tid];
        for (int k = 0; k < 64; k++) a += a1buf[k] * l2w[k * 32 + tid];
        a2buf[tid] = fmaxf(a, 0.f);
    }
    __syncthreads();
    if (tid == 0) {
        float t = l3b[0];
        for (int k = 0; k < 32; k++) t += a2buf[k] * l3w[k];
        out[b] = 1.0f / (1.0f + expf(-t));
    }
}

extern "C" void kernel_launch(void* const* d_in, const int* in_sizes, int n_in,
                              void* d_out, int out_size, void* d_ws, size_t ws_size,
                              hipStream_t stream) {
    const float* x   = (const float*)d_in[0];
    const int*   ei  = (const int*)d_in[1];
    const float* ew  = (const float*)d_in[2];
    const float* c1w = (const float*)d_in[4];
    const float* c1b = (const float*)d_in[5];
    const float* c2w = (const float*)d_in[6];
    const float* c2b = (const float*)d_in[7];
    const float* pw  = (const float*)d_in[8];
    const float* l1w = (const float*)d_in[9];
    const float* l1b = (const float*)d_in[10];
    const float* l2w = (const float*)d_in[11];
    const float* l2b = (const float*)d_in[12];
    const float* l3w = (const float*)d_in[13];
    const float* l3b = (const float*)d_in[14];
    float* out = (float*)d_out;
    int2* csr = (int2*)d_ws;
    (void)ws_size; (void)in_sizes; (void)n_in; (void)out_size;

    k_all<<<B_G, 1024, 0, stream>>>(ei, ew, x, c1w, c1b, c2w, c2b, pw,
                                    l1w, l1b, l2w, l2b, l3w, l3b, csr, out);
}